// Round 1
// baseline (2083.294 us; speedup 1.0000x reference)
//
#include <hip/hip_runtime.h>

// onering_conv_layer_batch: out[b,n,o] = bias[o] + sum_{j<448} W[o,j] * x[b, idx[m], c]
//   where f = n*448 + j, c = f / (7N), m = f mod (7N).
// Round 1: fused fp32 kernel. Block = 16 rows x 64 outputs, gather staged in LDS.

static constexpr int Bc   = 2;
static constexpr int Nv   = 163842;
static constexpr int CIN  = 64;
static constexpr int COUT = 64;
static constexpr int KK   = 448;                 // 7 * CIN
static constexpr unsigned SEVEN_N = 7u * 163842u; // 1146894
static constexpr int NBLK = 16;                  // rows per block
static constexpr int THREADS = 256;

__global__ __launch_bounds__(THREADS) void onering_conv_kernel(
    const float* __restrict__ x,     // (B, N, CIN)
    const float* __restrict__ W,     // (COUT, 448)
    const float* __restrict__ bias,  // (COUT,)
    const int*   __restrict__ idx,   // (7N,)
    float*       __restrict__ out)   // (B, N, COUT)
{
    __shared__ float v_lds[NBLK * KK];           // 16*448*4 = 28672 B

    const int tile = blockIdx.x;
    const int b    = blockIdx.y;
    const int n0   = tile * NBLK;
    const int t    = threadIdx.x;

    // Block's flat-f window is consecutive: f = n0*448 + e, e in [0, NBLK*448).
    // Channel increments at most once inside the window (7N >> NBLK*448).
    const unsigned f0 = (unsigned)n0 * KK;
    const unsigned c0 = f0 / SEVEN_N;
    const int nrows   = (Nv - n0 < NBLK) ? (Nv - n0) : NBLK;
    const unsigned valid = (unsigned)nrows * KK;
    const float* xb = x + (size_t)b * Nv * CIN;

    // ---- gather phase: random 4B reads, coalesced idx reads ----
    for (unsigned e = t; e < (unsigned)(NBLK * KK); e += THREADS) {
        float val = 0.0f;
        if (e < valid) {
            unsigned fz = f0 + e - c0 * SEVEN_N;
            unsigned c  = c0;
            if (fz >= SEVEN_N) { c += 1u; fz -= SEVEN_N; }
            const int vtx = idx[fz];
            val = xb[(size_t)vtx * CIN + c];
        }
        v_lds[e] = val;
    }
    __syncthreads();

    // ---- compute phase: wave g owns rows {4g..4g+3}, lane = output o ----
    const int o = t & 63;
    const int g = t >> 6;  // wave id 0..3
    const float* Wrow = W + o * KK;

    float acc[4] = {0.f, 0.f, 0.f, 0.f};
    for (int jc = 0; jc < KK / 4; ++jc) {
        const float4 wv = *reinterpret_cast<const float4*>(Wrow + jc * 4);
        #pragma unroll
        for (int i = 0; i < 4; ++i) {
            const float4 vv =
                *reinterpret_cast<const float4*>(&v_lds[(g * 4 + i) * KK + jc * 4]);
            acc[i] = fmaf(wv.x, vv.x, acc[i]);
            acc[i] = fmaf(wv.y, vv.y, acc[i]);
            acc[i] = fmaf(wv.z, vv.z, acc[i]);
            acc[i] = fmaf(wv.w, vv.w, acc[i]);
        }
    }

    const float bo = bias[o];
    #pragma unroll
    for (int i = 0; i < 4; ++i) {
        const int n = n0 + g * 4 + i;
        if (n < Nv) out[((size_t)b * Nv + n) * COUT + o] = acc[i] + bo;
    }
}

extern "C" void kernel_launch(void* const* d_in, const int* in_sizes, int n_in,
                              void* d_out, int out_size, void* d_ws, size_t ws_size,
                              hipStream_t stream) {
    const float* x    = (const float*)d_in[0];
    const float* W    = (const float*)d_in[1];
    const float* bias = (const float*)d_in[2];
    const int*   idx  = (const int*)d_in[3];
    float*       out  = (float*)d_out;

    dim3 grid((Nv + NBLK - 1) / NBLK, Bc);
    hipLaunchKernelGGL(onering_conv_kernel, grid, dim3(THREADS), 0, stream,
                       x, W, bias, idx, out);
}

// Round 2
// 392.054 us; speedup vs baseline: 5.3138x; 5.3138x over previous
//
#include <hip/hip_runtime.h>

typedef short bf8_t __attribute__((ext_vector_type(8)));   // 8 x bf16
typedef float f32x4 __attribute__((ext_vector_type(4)));

static constexpr int Bc      = 2;
static constexpr int Nv      = 163842;
static constexpr int CIN     = 64;
static constexpr int COUT    = 64;
static constexpr int KK      = 448;                 // 7*CIN
static constexpr int SEVEN_N = 7 * Nv;              // 1146894
static constexpr int Q       = 3;                   // rows per channel per tile
static constexpr int LM      = Q * KK;              // 1344
static constexpr int MSTAGE  = LM + KK;             // 1792 staged m-values (halo)
static constexpr int STRIDE  = 1816;                // LDS row stride (bf16): 908 dw % 32 = 12 -> <=2-way
static constexpr int NT      = (SEVEN_N + LM - 1) / LM;      // 854 m-tiles
static constexpr int PASSES  = (MSTAGE / 2) / 64;            // 14 gather passes

__device__ inline unsigned pack2_bf16(float a, float b) {
    unsigned ua = __builtin_bit_cast(unsigned, a);
    unsigned ub = __builtin_bit_cast(unsigned, b);
    ua = (ua + 0x7FFFu + ((ua >> 16) & 1u)) >> 16;          // RNE truncate
    ub = (ub + 0x7FFFu + ((ub >> 16) & 1u));
    return (ua & 0xFFFFu) | (ub & 0xFFFF0000u);
}

// Main: block = (m-tile mt, channel-group cg, batch b).
// Stages g[c][m] = x[b, idx[m], 16cg+c] for m in [M0, M0+MSTAGE) as bf16 in LDS,
// then computes, for each of 16 channels, Q full output rows via MFMA.
__global__ __launch_bounds__(256, 2) void conv_main(
    const float* __restrict__ x,
    const short* __restrict__ Wb,      // bf16 W, row-major [COUT][KK]
    const float* __restrict__ bias,
    const int*   __restrict__ idx,
    float*       __restrict__ out)
{
    __shared__ short tile[16 * STRIDE];                      // 58112 B

    const int t  = threadIdx.x;
    const int mt = blockIdx.x;
    const int cg = blockIdx.y;
    const int b  = blockIdx.z;
    const int M0 = mt * LM;
    const int mEnd = min(M0 + MSTAGE, SEVEN_N);
    const float* xb = x + (size_t)b * Nv * CIN;

    const int lane = t & 63;
    const int w    = t >> 6;          // wave id = o-chunk (16 outputs)
    const int col  = lane & 15;
    const int hi   = lane >> 4;       // k-octet selector

    // ---- preload B fragments: B[k][o] = W[o][k], lane(col=o, hi=k-octet) ----
    const short* wrow = Wb + (w * 16 + col) * KK + 8 * hi;
    bf8_t bfrag[14];
    #pragma unroll
    for (int k0 = 0; k0 < 14; ++k0)
        bfrag[k0] = *(const bf8_t*)(wrow + 32 * k0);

    // ---- gather phase: 4 threads per m-pair, each does 4 channels ----
    const int q    = t & 3;           // channel quad
    const int pidl = t >> 2;          // pair id within pass (0..63)
    const int xoff = cg * 16 + q * 4;

    int iv0[PASSES], iv1[PASSES];
    #pragma unroll
    for (int p = 0; p < PASSES; ++p) {
        const int m0 = M0 + 2 * (p * 64 + pidl);
        iv0[p] = (m0     < mEnd) ? idx[m0]     : 0;
        iv1[p] = (m0 + 1 < mEnd) ? idx[m0 + 1] : 0;
    }
    #pragma unroll
    for (int p = 0; p < PASSES; ++p) {
        const int pid = p * 64 + pidl;
        const int m0  = M0 + 2 * pid;
        if (m0 < mEnd) {
            const float4 v0 = *(const float4*)(xb + (size_t)iv0[p] * CIN + xoff);
            float4 v1 = make_float4(0.f, 0.f, 0.f, 0.f);
            if (m0 + 1 < mEnd)
                v1 = *(const float4*)(xb + (size_t)iv1[p] * CIN + xoff);
            const float a0[4] = {v0.x, v0.y, v0.z, v0.w};
            const float a1[4] = {v1.x, v1.y, v1.z, v1.w};
            #pragma unroll
            for (int i = 0; i < 4; ++i) {
                const int c     = q * 4 + i;
                const int shift = (6 * c) & 7;               // = T mod 8, always even
                const int ppos  = (m0 - M0) + shift;
                *(unsigned*)&tile[c * STRIDE + ppos] = pack2_bf16(a0[i], a1[i]);
            }
        }
    }
    __syncthreads();

    // ---- compute: MFMA rows = 16 channels, cols = 16 outputs, K = 448 ----
    // A-row params for this lane's channel (c = col)
    const int Ca  = cg * 16 + col;
    const int Ta  = Ca * SEVEN_N + M0;
    const int d0a = (448 - (Ta % 448)) % 448;   // first row start rel. to M0
    const int sha = Ta & 7;                     // staging shift (16B alignment)
    const short* abase = &tile[col * STRIDE + d0a + sha + 8 * hi];

    f32x4 acc[Q];
    #pragma unroll
    for (int r = 0; r < Q; ++r) acc[r] = (f32x4){0.f, 0.f, 0.f, 0.f};

    #pragma unroll
    for (int k0 = 0; k0 < 14; ++k0) {
        #pragma unroll
        for (int r = 0; r < Q; ++r) {
            const bf8_t afrag = *(const bf8_t*)(abase + 448 * r + 32 * k0);
            acc[r] = __builtin_amdgcn_mfma_f32_16x16x32_bf16(afrag, bfrag[k0], acc[r], 0, 0, 0);
        }
    }

    // ---- store: D[row=c][col=o], row = 4*hi + reg ----
    const float bo = bias[w * 16 + col];
    #pragma unroll
    for (int i = 0; i < 4; ++i) {
        const int c_s = 4 * hi + i;
        const int Cs  = cg * 16 + c_s;
        const int Ts  = Cs * SEVEN_N + M0;
        const int d0s = (448 - (Ts % 448)) % 448;
        const int nf  = (Ts + d0s) / 448;       // first row n in this tile
        #pragma unroll
        for (int r = 0; r < Q; ++r) {
            const int sr = M0 + d0s + 448 * r;  // absolute m-start of row
            if (sr + 448 <= SEVEN_N) {          // skip channel-straddling rows
                const int n = nf + r;
                out[((size_t)b * Nv + n) * COUT + w * 16 + col] = acc[r][i] + bo;
            }
        }
    }
}

// Rows whose 448-window crosses a channel boundary: exact fp32.
__global__ void conv_cleanup(const float* __restrict__ x,
                             const float* __restrict__ W,
                             const float* __restrict__ bias,
                             const int*   __restrict__ idx,
                             float*       __restrict__ out)
{
    const int C = blockIdx.x;                   // 0..63
    const int b = blockIdx.y;
    const int o = threadIdx.x;                  // 0..63
    const int n = ((C + 1) * SEVEN_N + 447) / 448 - 1;   // last row of channel C
    const int s = 448 * n - C * SEVEN_N;
    if (s + 448 <= SEVEN_N) return;             // no straddle at this boundary
    const float* xb = x + (size_t)b * Nv * CIN;
    float acc = bias[o];
    for (int j = 0; j < 448; ++j) {
        int m = s + j, c = C;
        if (m >= SEVEN_N) { m -= SEVEN_N; c += 1; }
        acc += xb[(size_t)idx[m] * CIN + c] * W[o * KK + j];
    }
    out[((size_t)b * Nv + n) * COUT + o] = acc;
}

__global__ void wconv(const float* __restrict__ W, short* __restrict__ Wb) {
    const int i = blockIdx.x * 256 + threadIdx.x;
    if (i < COUT * KK) {
        unsigned u = __builtin_bit_cast(unsigned, W[i]);
        u = (u + 0x7FFFu + ((u >> 16) & 1u)) >> 16;
        Wb[i] = (short)u;
    }
}

extern "C" void kernel_launch(void* const* d_in, const int* in_sizes, int n_in,
                              void* d_out, int out_size, void* d_ws, size_t ws_size,
                              hipStream_t stream) {
    const float* x    = (const float*)d_in[0];
    const float* W    = (const float*)d_in[1];
    const float* bias = (const float*)d_in[2];
    const int*   idx  = (const int*)d_in[3];
    float*       out  = (float*)d_out;
    short*       Wb   = (short*)d_ws;           // 57344 B of scratch

    hipLaunchKernelGGL(wconv, dim3((COUT * KK + 255) / 256), dim3(256), 0, stream, W, Wb);
    hipLaunchKernelGGL(conv_main, dim3(NT, 4, Bc), dim3(256), 0, stream,
                       x, Wb, bias, idx, out);
    hipLaunchKernelGGL(conv_cleanup, dim3(CIN, Bc), dim3(64), 0, stream,
                       x, W, bias, idx, out);
}

// Round 3
// 285.864 us; speedup vs baseline: 7.2877x; 1.3715x over previous
//
#include <hip/hip_runtime.h>

typedef short bf8_t __attribute__((ext_vector_type(8)));   // 8 x bf16
typedef float f32x4 __attribute__((ext_vector_type(4)));

static constexpr int Bc      = 2;
static constexpr int Nv      = 163842;
static constexpr int CIN     = 64;
static constexpr int COUT    = 64;
static constexpr int KK      = 448;                 // 7*CIN
static constexpr int SEVEN_N = 7 * Nv;              // 1146894
static constexpr int Q       = 3;                   // rows per channel per tile
static constexpr int LM      = Q * KK;              // 1344 (== 0 mod 8)
static constexpr int MSTAGE  = LM + KK;             // 1792 staged m-values (halo)
static constexpr int STRIDE  = 1800;                // 900 dw; 900%32=4 -> 2-way (free)
static constexpr int NT      = (SEVEN_N + LM - 1) / LM;      // 854 m-tiles
static constexpr int THREADS = 768;                 // 12 waves
static constexpr int PAIRS   = MSTAGE / 2;          // 896
static constexpr int PPP     = THREADS / 4;         // 192 pairs per pass
static constexpr int PASSES  = (PAIRS + PPP - 1) / PPP;      // 5

__device__ inline unsigned pack2_bf16(float a, float b) {
    unsigned ua = __builtin_bit_cast(unsigned, a);
    unsigned ub = __builtin_bit_cast(unsigned, b);
    ua = (ua + 0x7FFFu + ((ua >> 16) & 1u)) >> 16;          // RNE
    ub = (ub + 0x7FFFu + ((ub >> 16) & 1u));
    return (ua & 0xFFFFu) | (ub & 0xFFFF0000u);
}

// Block = (m-tile, channel-group, batch). 12 waves: gather MSTAGE m-values x
// 16 channels into LDS (bf16), then each wave computes one output row-slot
// (oc = w&3 -> 16 outputs, r = w>>2 -> row) via 14 MFMAs.
__global__ __launch_bounds__(THREADS, 6) void conv_main(
    const float* __restrict__ x,
    const short* __restrict__ Wb,      // bf16 W, row-major [COUT][KK]
    const float* __restrict__ bias,
    const int*   __restrict__ idx,
    float*       __restrict__ out)
{
    __shared__ short tile[16 * STRIDE];                      // 57600 B -> 2 blk/CU

    const int t  = threadIdx.x;
    const int mt = blockIdx.x;
    const int cg = blockIdx.y;
    const int b  = blockIdx.z;
    const int M0 = mt * LM;
    const int mEnd = min(M0 + MSTAGE, SEVEN_N);
    const float* xb = x + (size_t)b * Nv * CIN;

    // ---- gather: 4 threads per m-pair (one per channel-quad) ----
    const int q    = t & 3;
    const int pidl = t >> 2;          // 0..191
    const int xoff = cg * 16 + q * 4;

    int iv0[PASSES], iv1[PASSES];
    #pragma unroll
    for (int p = 0; p < PASSES; ++p) {
        const int pid = p * PPP + pidl;
        const int m0  = M0 + 2 * pid;
        const bool ok = (pid < PAIRS) && (m0 < mEnd);
        iv0[p] = ok ? idx[m0] : 0;
        iv1[p] = (ok && m0 + 1 < mEnd) ? idx[m0 + 1] : 0;
    }
    #pragma unroll
    for (int p = 0; p < PASSES; ++p) {
        const int pid = p * PPP + pidl;
        const int m0  = M0 + 2 * pid;
        if (pid < PAIRS && m0 < mEnd) {
            const float4 v0 = *(const float4*)(xb + (size_t)iv0[p] * CIN + xoff);
            float4 v1 = make_float4(0.f, 0.f, 0.f, 0.f);
            if (m0 + 1 < mEnd)
                v1 = *(const float4*)(xb + (size_t)iv1[p] * CIN + xoff);
            const float a0[4] = {v0.x, v0.y, v0.z, v0.w};
            const float a1[4] = {v1.x, v1.y, v1.z, v1.w};
            #pragma unroll
            for (int i = 0; i < 4; ++i) {
                const int c     = q * 4 + i;
                const int shift = (6 * c) & 7;               // == (Ta&7), even
                const int ppos  = (m0 - M0) + shift;
                *(unsigned*)&tile[c * STRIDE + ppos] = pack2_bf16(a0[i], a1[i]);
            }
        }
    }
    __syncthreads();

    // ---- compute: wave w -> o-chunk (w&3), row slot (w>>2) ----
    const int lane = t & 63;
    const int w    = t >> 6;          // 0..11
    const int oc   = w & 3;
    const int r    = w >> 2;          // 0..2
    const int col  = lane & 15;
    const int hi   = lane >> 4;

    const short* wbase = Wb + (oc * 16 + col) * KK + 8 * hi;

    const int Ca  = cg * 16 + col;
    const int Ta  = Ca * SEVEN_N + M0;
    const int d0a = (448 - (Ta % 448)) % 448;
    const int sha = Ta & 7;                                  // keeps reads 16B-aligned
    const short* abase = &tile[col * STRIDE + d0a + sha + 8 * hi + 448 * r];

    f32x4 acc = (f32x4){0.f, 0.f, 0.f, 0.f};
    #pragma unroll
    for (int k0 = 0; k0 < 14; ++k0) {
        const bf8_t bfrag = *(const bf8_t*)(wbase + 32 * k0);
        const bf8_t afrag = *(const bf8_t*)(abase + 32 * k0);
        acc = __builtin_amdgcn_mfma_f32_16x16x32_bf16(afrag, bfrag, acc, 0, 0, 0);
    }

    // ---- store: D[row=channel][col=o], channel = 4*hi + i ----
    const float bo = bias[oc * 16 + col];
    #pragma unroll
    for (int i = 0; i < 4; ++i) {
        const int c_s = 4 * hi + i;
        const int Cs  = cg * 16 + c_s;
        const int Ts  = Cs * SEVEN_N + M0;
        const int d0s = (448 - (Ts % 448)) % 448;
        const int sr  = M0 + d0s + 448 * r;      // absolute m-start of this row
        if (sr + 448 <= SEVEN_N) {               // skip channel-straddling rows
            const int n = (Ts + d0s) / 448 + r;
            out[((size_t)b * Nv + n) * COUT + oc * 16 + col] = acc[i] + bo;
        }
    }
}

// Channel-straddling rows (<=63 per batch): exact fp32, j-parallel.
__global__ __launch_bounds__(256) void conv_cleanup(
    const float* __restrict__ x,
    const float* __restrict__ W,
    const float* __restrict__ bias,
    const int*   __restrict__ idx,
    float*       __restrict__ out)
{
    __shared__ float part[4][64];
    const int C = blockIdx.x;                    // 0..63
    const int b = blockIdx.y;
    const int t = threadIdx.x;
    const int o = t & 63;
    const int p = t >> 6;                        // j-quarter
    const int n = (int)(((long long)(C + 1) * SEVEN_N + 447) / 448) - 1;
    const int s = 448 * n - C * SEVEN_N;
    if (s + 448 <= SEVEN_N) return;              // no straddle at this boundary
    const float* xb = x + (size_t)b * Nv * CIN;
    float acc = 0.f;
    for (int j = p * 112; j < (p + 1) * 112; ++j) {
        int m = s + j, c = C;
        if (m >= SEVEN_N) { m -= SEVEN_N; c += 1; }
        acc += xb[(size_t)idx[m] * CIN + c] * W[o * KK + j];
    }
    part[p][o] = acc;
    __syncthreads();
    if (p == 0)
        out[((size_t)b * Nv + n) * COUT + o] =
            part[0][o] + part[1][o] + part[2][o] + part[3][o] + bias[o];
}

__global__ void wconv(const float* __restrict__ W, short* __restrict__ Wb) {
    const int i = blockIdx.x * 256 + threadIdx.x;
    if (i < COUT * KK) {
        unsigned u = __builtin_bit_cast(unsigned, W[i]);
        u = (u + 0x7FFFu + ((u >> 16) & 1u)) >> 16;
        Wb[i] = (short)u;
    }
}

extern "C" void kernel_launch(void* const* d_in, const int* in_sizes, int n_in,
                              void* d_out, int out_size, void* d_ws, size_t ws_size,
                              hipStream_t stream) {
    const float* x    = (const float*)d_in[0];
    const float* W    = (const float*)d_in[1];
    const float* bias = (const float*)d_in[2];
    const int*   idx  = (const int*)d_in[3];
    float*       out  = (float*)d_out;
    short*       Wb   = (short*)d_ws;           // 57344 B scratch

    hipLaunchKernelGGL(wconv, dim3((COUT * KK + 255) / 256), dim3(256), 0, stream, W, Wb);
    hipLaunchKernelGGL(conv_main, dim3(NT, 4, Bc), dim3(THREADS), 0, stream,
                       x, Wb, bias, idx, out);
    hipLaunchKernelGGL(conv_cleanup, dim3(CIN, Bc), dim3(256), 0, stream,
                       x, W, bias, idx, out);
}

// Round 4
// 253.941 us; speedup vs baseline: 8.2038x; 1.1257x over previous
//
#include <hip/hip_runtime.h>

typedef short bf8_t __attribute__((ext_vector_type(8)));   // 8 x bf16
typedef float f32x4 __attribute__((ext_vector_type(4)));

static constexpr int Bc      = 2;
static constexpr int Nv      = 163842;
static constexpr int CIN     = 64;
static constexpr int COUT    = 64;
static constexpr int KK      = 448;                 // 7*CIN
static constexpr int SEVEN_N = 7 * Nv;              // 1146894
static constexpr int Q       = 3;                   // rows per channel per tile
static constexpr int LM      = Q * KK;              // 1344
static constexpr int MSTAGE  = LM + KK;             // 1792 staged m-values (halo)
static constexpr int STRIDE  = 1800;                // 900 dw; 900%32=4 -> 2-way (free)
static constexpr int NT      = (SEVEN_N + LM - 1) / LM;      // 854 m-tiles
static constexpr int THREADS = 512;                 // 8 waves
static constexpr int PAIRS   = MSTAGE / 2;          // 896
static constexpr int PPP     = THREADS / 4;         // 128 pairs per pass
static constexpr int PASSES  = PAIRS / PPP;         // 7 (exact)

__device__ inline unsigned pack2_bf16(float a, float b) {
    unsigned ua = __builtin_bit_cast(unsigned, a);
    unsigned ub = __builtin_bit_cast(unsigned, b);
    ua = (ua + 0x7FFFu + ((ua >> 16) & 1u)) >> 16;          // RNE
    ub = (ub + 0x7FFFu + ((ub >> 16) & 1u));
    return (ua & 0xFFFFu) | (ub & 0xFFFF0000u);
}

// 1D grid, XCD-affinity decode: slot = bid&7 -> (cg,b); mt = bid>>3.
// All blocks touching x-slab (b, channels 16cg..16cg+15) run on one XCD's L2.
__global__ __launch_bounds__(THREADS, 4) void conv_main(
    const float* __restrict__ x,
    const short* __restrict__ Wb,      // bf16 W, row-major [COUT][KK]
    const float* __restrict__ bias,
    const int*   __restrict__ idx,
    float*       __restrict__ out)
{
    __shared__ short tile[16 * STRIDE];                      // 57600 B -> 2 blk/CU

    const int bid  = blockIdx.x;
    const int slot = bid & 7;
    const int cg   = slot >> 1;
    const int b    = slot & 1;
    const int mt   = bid >> 3;
    const int t    = threadIdx.x;
    const int M0   = mt * LM;
    const int mEnd = min(M0 + MSTAGE, SEVEN_N);
    const float* xb = x + (size_t)b * Nv * CIN;

    // ---- gather: 4 threads per m-pair; ALL loads issued before any LDS write ----
    const int q    = t & 3;
    const int pidl = t >> 2;          // 0..127
    const int xoff = cg * 16 + q * 4;

    int iv0[PASSES], iv1[PASSES];
    #pragma unroll
    for (int p = 0; p < PASSES; ++p) {
        const int m0 = M0 + 2 * (p * PPP + pidl);
        const bool ok = (m0 < mEnd);
        iv0[p] = ok ? idx[m0] : 0;
        iv1[p] = (ok && m0 + 1 < mEnd) ? idx[m0 + 1] : 0;
    }
    float4 v0[PASSES], v1[PASSES];
    #pragma unroll
    for (int p = 0; p < PASSES; ++p) {   // 14 independent 16B loads in flight
        v0[p] = *(const float4*)(xb + (size_t)iv0[p] * CIN + xoff);
        v1[p] = *(const float4*)(xb + (size_t)iv1[p] * CIN + xoff);
    }
    #pragma unroll
    for (int p = 0; p < PASSES; ++p) {
        const int m0 = M0 + 2 * (p * PPP + pidl);
        if (m0 < mEnd) {
            const float a0[4] = {v0[p].x, v0[p].y, v0[p].z, v0[p].w};
            const float a1[4] = {v1[p].x, v1[p].y, v1[p].z, v1[p].w};
            #pragma unroll
            for (int i = 0; i < 4; ++i) {
                const int c     = q * 4 + i;
                const int shift = (6 * c) & 7;               // == Ta&7, even
                const int ppos  = (m0 - M0) + shift;
                *(unsigned*)&tile[c * STRIDE + ppos] = pack2_bf16(a0[i], a1[i]);
            }
        }
    }
    __syncthreads();

    // ---- compute: 12 tasks (oc = task&3, r = task>>2) over 8 waves ----
    const int lane = t & 63;
    const int w    = t >> 6;          // 0..7
    const int col  = lane & 15;
    const int hi   = lane >> 4;
    const int oc   = w & 3;           // same for task w and w+8 -> share bfrag

    const short* wbase = Wb + (oc * 16 + col) * KK + 8 * hi;
    bf8_t bfrag[14];
    #pragma unroll
    for (int k0 = 0; k0 < 14; ++k0)
        bfrag[k0] = *(const bf8_t*)(wbase + 32 * k0);

    const int Ca  = cg * 16 + col;
    const int Ta  = Ca * SEVEN_N + M0;
    const int d0a = (448 - (Ta % 448)) % 448;
    const int sha = Ta & 7;
    const short* abase0 = &tile[col * STRIDE + d0a + sha + 8 * hi];
    const float bo = bias[oc * 16 + col];

    for (int task = w; task < 12; task += 8) {
        const int r = task >> 2;                 // 0..2
        const short* abase = abase0 + 448 * r;

        f32x4 acc = (f32x4){0.f, 0.f, 0.f, 0.f};
        #pragma unroll
        for (int k0 = 0; k0 < 14; ++k0) {
            const bf8_t afrag = *(const bf8_t*)(abase + 32 * k0);
            acc = __builtin_amdgcn_mfma_f32_16x16x32_bf16(afrag, bfrag[k0], acc, 0, 0, 0);
        }

        // D[row=channel][col=o], channel = 4*hi + i
        #pragma unroll
        for (int i = 0; i < 4; ++i) {
            const int c_s = 4 * hi + i;
            const int Cs  = cg * 16 + c_s;
            const int Ts  = Cs * SEVEN_N + M0;
            const int d0s = (448 - (Ts % 448)) % 448;
            const int sr  = M0 + d0s + 448 * r;
            if (sr + 448 <= SEVEN_N) {           // skip channel-straddling rows
                const int n = (Ts + d0s) / 448 + r;
                out[((size_t)b * Nv + n) * COUT + oc * 16 + col] = acc[i] + bo;
            }
        }
    }
}

// Channel-straddling rows (<=63 per batch): exact fp32, j-parallel.
__global__ __launch_bounds__(256) void conv_cleanup(
    const float* __restrict__ x,
    const float* __restrict__ W,
    const float* __restrict__ bias,
    const int*   __restrict__ idx,
    float*       __restrict__ out)
{
    __shared__ float part[4][64];
    const int C = blockIdx.x;                    // 0..63
    const int b = blockIdx.y;
    const int t = threadIdx.x;
    const int o = t & 63;
    const int p = t >> 6;                        // j-quarter
    const int n = (int)(((long long)(C + 1) * SEVEN_N + 447) / 448) - 1;
    const int s = 448 * n - C * SEVEN_N;
    if (s + 448 <= SEVEN_N) return;              // no straddle at this boundary
    const float* xb = x + (size_t)b * Nv * CIN;
    float acc = 0.f;
    for (int j = p * 112; j < (p + 1) * 112; ++j) {
        int m = s + j, c = C;
        if (m >= SEVEN_N) { m -= SEVEN_N; c += 1; }
        acc += xb[(size_t)idx[m] * CIN + c] * W[o * KK + j];
    }
    part[p][o] = acc;
    __syncthreads();
    if (p == 0)
        out[((size_t)b * Nv + n) * COUT + o] =
            part[0][o] + part[1][o] + part[2][o] + part[3][o] + bias[o];
}

__global__ void wconv(const float* __restrict__ W, short* __restrict__ Wb) {
    const int i = blockIdx.x * 256 + threadIdx.x;
    if (i < COUT * KK) {
        unsigned u = __builtin_bit_cast(unsigned, W[i]);
        u = (u + 0x7FFFu + ((u >> 16) & 1u)) >> 16;
        Wb[i] = (short)u;
    }
}

extern "C" void kernel_launch(void* const* d_in, const int* in_sizes, int n_in,
                              void* d_out, int out_size, void* d_ws, size_t ws_size,
                              hipStream_t stream) {
    const float* x    = (const float*)d_in[0];
    const float* W    = (const float*)d_in[1];
    const float* bias = (const float*)d_in[2];
    const int*   idx  = (const int*)d_in[3];
    float*       out  = (float*)d_out;
    short*       Wb   = (short*)d_ws;           // 57344 B scratch

    hipLaunchKernelGGL(wconv, dim3((COUT * KK + 255) / 256), dim3(256), 0, stream, W, Wb);
    hipLaunchKernelGGL(conv_main, dim3(NT * 8), dim3(THREADS), 0, stream,
                       x, Wb, bias, idx, out);
    hipLaunchKernelGGL(conv_cleanup, dim3(CIN, Bc), dim3(256), 0, stream,
                       x, W, bias, idx, out);
}